// Round 26
// baseline (109.968 us; speedup 1.0000x reference)
//
#include <hip/hip_runtime.h>
#include <math.h>

#define D 64
#define BN_EPS 1e-5f

#define NBITS 7                 // 128 nodes per bin
#define BINSZ 128
#define MAXBINS 800             // >= ceil(100000/128)=782
#define CAP 2048                // per-bin edge capacity (mean 1535)
#define CHUNK 2048              // edges per binA workgroup -> 586 WGs (R26: was 4096)
#define BUCKET 48               // per-node capacity (Poisson(12) tail @48 ~ 1e-15)
#define OP 68                   // fp32 tile stride (272B: 16B-aligned rows)
#define WP 72                   // bf16 weight tile stride (144B: 16B-aligned rows)

typedef short bf16x8 __attribute__((ext_vector_type(8)));
typedef float f32x4 __attribute__((ext_vector_type(4)));

__device__ __forceinline__ unsigned f2bf(float f) {
    unsigned u = __float_as_uint(f);
    return (u + 0x7FFFu + ((u >> 16) & 1u)) >> 16;   // RNE
}
__device__ __forceinline__ float bf2f(unsigned short h) {
    return __uint_as_float(((unsigned)h) << 16);
}

// ---------------------------------------------------------------------------
// Tiny zero kernel for binCursor (must complete before binA's atomics).
// ---------------------------------------------------------------------------
__global__ __launch_bounds__(256) void zero_kernel(int4* __restrict__ p, int n4) {
    int t = blockIdx.x * 256 + threadIdx.x;
    if (t < n4) p[t] = make_int4(0, 0, 0, 0);
}

// ---------------------------------------------------------------------------
// Pass A: x->bf16 conversion (grid-stride prologue, independent) + bin edges
// by dst>>7. CHUNK=2048 -> 586 WGs: conversion streams at ~full BW while the
// sort phases are atomic/latency-bound (R26 merge; removes xhalf dispatch).
// ---------------------------------------------------------------------------
__global__ __launch_bounds__(1024) void binA_kernel(
    const int* __restrict__ ei, int* __restrict__ binCursor,   // padded x16
    unsigned* __restrict__ binBuf, const float* __restrict__ x,
    unsigned short* __restrict__ xh, long long n8, int E, int nbins) {
    __shared__ unsigned short pos[CHUNK];
    __shared__ int hist[MAXBINS];
    __shared__ int base[MAXBINS];
    int tid = threadIdx.x;
    int c0 = blockIdx.x * CHUNK;

    // prologue: x -> bf16 (independent of sort; no barrier needed before it)
    for (long long t = (long long)blockIdx.x * 1024 + tid; t < n8;
         t += (long long)gridDim.x * 1024) {
        const float4* rp = (const float4*)(x + t * 8);
        float4 a = rp[0], b = rp[1];
        uint4 o;
        o.x = f2bf(a.x) | (f2bf(a.y) << 16);
        o.y = f2bf(a.z) | (f2bf(a.w) << 16);
        o.z = f2bf(b.x) | (f2bf(b.y) << 16);
        o.w = f2bf(b.z) | (f2bf(b.w) << 16);
        *(uint4*)(xh + t * 8) = o;
    }

    for (int i = tid; i < nbins; i += 1024) hist[i] = 0;
    __syncthreads();

#pragma unroll
    for (int k = 0; k < CHUNK / 1024; ++k) {
        int i = k * 1024 + tid;
        int e = c0 + i;
        if (e < E) {
            int dst = ei[E + e];
            pos[i] = (unsigned short)atomicAdd(&hist[dst >> NBITS], 1);
        }
    }
    __syncthreads();

    for (int b = tid; b < nbins; b += 1024) {
        int h = hist[b];
        base[b] = h > 0 ? atomicAdd(&binCursor[b * 16], h) : 0;
    }
    __syncthreads();

#pragma unroll
    for (int k = 0; k < CHUNK / 1024; ++k) {
        int i = k * 1024 + tid;
        int e = c0 + i;
        if (e < E) {
            int src = ei[e];
            int dst = ei[E + e];
            int b = dst >> NBITS;
            int idx = base[b] + (int)pos[i];
            if (idx < CAP)
                binBuf[(size_t)b * CAP + idx] =
                    ((unsigned)src << NBITS) | (unsigned)(dst & (BINSZ - 1));
        }
    }
}

// ---------------------------------------------------------------------------
// FUSED sort + gather + mean + root + linear(MFMA) + BN partials
// (unchanged R23/R25, proven 49.5us / passing).
// ---------------------------------------------------------------------------
__global__ __launch_bounds__(1024) void fusedGLS_kernel(
    const unsigned short* __restrict__ xh, const unsigned* __restrict__ binBuf,
    const int* __restrict__ binCursor, const float* __restrict__ W,
    const float* __restrict__ bias, float* __restrict__ h,
    float* __restrict__ partial, int N) {
    __shared__ unsigned short wt[64 * WP];     // 9.2KB  W bf16
    __shared__ unsigned short ta[64 * WP];     // 9.2KB  hpre bf16
    __shared__ float uni[64 * OP];             // 17.4KB lcsr (phase1-2) / out (phase3)
    __shared__ int hist[64];
    __shared__ float psum[16 * 32];
    int* lcsr = (int*)uni;

    int tid = threadIdx.x;
    int lane = tid & 63;
    int w = tid >> 6;                          // wave 0..15
    int rbase = blockIdx.x << 6;
    int bin = blockIdx.x >> 1, half = blockIdx.x & 1;
    int nrows = N - rbase; if (nrows > 64) nrows = 64;

    // phase 0: stage W -> bf16; zero hist
    {
        int r = tid >> 4, q = tid & 15;
        float4 v = *(const float4*)(W + (size_t)r * D + q * 4);
        uint2 o;
        o.x = f2bf(v.x) | (f2bf(v.y) << 16);
        o.y = f2bf(v.z) | (f2bf(v.w) << 16);
        *(uint2*)(wt + r * WP + q * 4) = o;
    }
    if (tid < 64) hist[tid] = 0;
    __syncthreads();

    // phase 1: inline counting sort of this half-bin (LDS atomics only)
    {
        int nE = binCursor[bin * 16]; if (nE > CAP) nE = CAP;
        const unsigned* eb = binBuf + (size_t)bin * CAP;
        for (int i = tid; i < nE; i += 1024) {
            unsigned r = eb[i];
            int dl = (int)(r & (BINSZ - 1));
            if ((dl >> 6) == half) {
                int d2 = dl & 63;
                int p = atomicAdd(&hist[d2], 1);
                if (p < BUCKET) lcsr[d2 * BUCKET + p] = (int)(r >> NBITS);
            }
        }
    }
    __syncthreads();

    // phase 2: gather 4 nodes per wave into ta rows 4w..4w+3 (bf16)
    int c = lane & 15, g = lane >> 4;
    for (int i = 0; i < 4; ++i) {
        int nl = w * 4 + i;
        int node = rbase + nl;
        if (node < N) {
            int deg = hist[nl];
            deg = __builtin_amdgcn_readfirstlane(deg);
            int trips = deg < BUCKET ? deg : BUCKET;
            int sidx = lane < BUCKET ? lcsr[nl * BUCKET + lane] : 0;
            float a0 = 0.f, a1 = 0.f, a2 = 0.f, a3 = 0.f;
            if (trips > 0) {
                int nq = (trips + 3) >> 2;        // <= 12, wave-uniform
                int last = trips - 1;
                uint2 v[12];
#pragma unroll
                for (int q = 0; q < 12; ++q) {
                    if (q < nq) {
                        int r = 4 * q + g;
                        int rc = r < trips ? r : last;
                        int s = __shfl(sidx, rc);
                        v[q] = *(const uint2*)(xh + (size_t)s * D + c * 4);
                    }
                }
#pragma unroll
                for (int q = 0; q < 12; ++q) {
                    if (q < nq) {
                        int r = 4 * q + g;
                        if (r < trips) {
                            unsigned lo = v[q].x, hi = v[q].y;
                            a0 += __uint_as_float(lo << 16);
                            a1 += __uint_as_float(lo & 0xFFFF0000u);
                            a2 += __uint_as_float(hi << 16);
                            a3 += __uint_as_float(hi & 0xFFFF0000u);
                        }
                    }
                }
            }
            a0 += __shfl_xor(a0, 16); a0 += __shfl_xor(a0, 32);
            a1 += __shfl_xor(a1, 16); a1 += __shfl_xor(a1, 32);
            a2 += __shfl_xor(a2, 16); a2 += __shfl_xor(a2, 32);
            a3 += __shfl_xor(a3, 16); a3 += __shfl_xor(a3, 32);
            float invd = deg > 0 ? 1.0f / (float)deg : 1.0f;   // /max(deg,1)
            if (g == 0) {
                uint2 rt = *(const uint2*)(xh + (size_t)node * D + c * 4);
                float f0 = __uint_as_float(rt.x << 16)         + a0 * invd;
                float f1 = __uint_as_float(rt.x & 0xFFFF0000u) + a1 * invd;
                float f2 = __uint_as_float(rt.y << 16)         + a2 * invd;
                float f3 = __uint_as_float(rt.y & 0xFFFF0000u) + a3 * invd;
                uint2 o;
                o.x = f2bf(f0) | (f2bf(f1) << 16);
                o.y = f2bf(f2) | (f2bf(f3) << 16);
                *(uint2*)(ta + nl * WP + c * 4) = o;
            }
        } else if (g == 0) {
            *(uint2*)(ta + nl * WP + c * 4) = make_uint2(0u, 0u);
        }
    }
    __syncthreads();   // ta complete; all lcsr reads done (uni now free)

    // phase 3: MFMA. wave w -> row-block rb=w&3, col-chunk t=w>>2.
    int rb = w & 3, t = w >> 2;
    int ar = lane & 15, gg = lane >> 4;
    bf16x8 A0 = *(const bf16x8*)(ta + (rb * 16 + ar) * WP + 8 * gg);
    bf16x8 A1 = *(const bf16x8*)(ta + (rb * 16 + ar) * WP + 32 + 8 * gg);
    bf16x8 B0 = *(const bf16x8*)(wt + (t * 16 + ar) * WP + 8 * gg);
    bf16x8 B1 = *(const bf16x8*)(wt + (t * 16 + ar) * WP + 32 + 8 * gg);
    float bj = bias[t * 16 + ar];
    f32x4 acc;
    acc[0] = bj; acc[1] = bj; acc[2] = bj; acc[3] = bj;
    acc = __builtin_amdgcn_mfma_f32_16x16x32_bf16(A0, B0, acc, 0, 0, 0);
    acc = __builtin_amdgcn_mfma_f32_16x16x32_bf16(A1, B1, acc, 0, 0, 0);

    // write output block into uni (lcsr dead since pre-MFMA barrier)
#pragma unroll
    for (int r = 0; r < 4; ++r)
        uni[(rb * 16 + 4 * gg + r) * OP + t * 16 + ar] = acc[r];
    float s = 0.f, q = 0.f;
#pragma unroll
    for (int r = 0; r < 4; ++r) {
        int row = rb * 16 + 4 * gg + r;
        float v = (row < nrows) ? acc[r] : 0.f;
        s += v; q += v * v;
    }
    s += __shfl_xor(s, 16); s += __shfl_xor(s, 32);
    q += __shfl_xor(q, 16); q += __shfl_xor(q, 32);
    if (lane < 16) {
        psum[w * 32 + lane] = s;
        psum[w * 32 + 16 + lane] = q;
    }
    __syncthreads();

    // contiguous store (1024 threads = 64 rows x 16 quads)
    {
        int r = tid >> 4, cq = tid & 15;
        if (r < nrows)
            *(float4*)(h + (size_t)(rbase + r) * D + cq * 4) =
                *(const float4*)(uni + r * OP + cq * 4);
    }
    // per-WG partial write
    if (tid < 128) {
        int f = tid & 63;
        int off = (tid >= 64) ? 16 : 0;
        int t2 = f >> 4, col = f & 15;
        float a = 0.f;
#pragma unroll
        for (int rb2 = 0; rb2 < 4; ++rb2)
            a += psum[(t2 * 4 + rb2) * 32 + off + col];
        partial[(size_t)blockIdx.x * 128 + tid] = a;
    }
}

// ---------------------------------------------------------------------------
// Parallel BN reduce + finalize (unchanged R17).
// ---------------------------------------------------------------------------
__global__ __launch_bounds__(256) void reduceBN_kernel(
    const float* __restrict__ partial, const float* __restrict__ gamma,
    const float* __restrict__ beta, float* __restrict__ ss,
    int nWG, float inv_n) {
    __shared__ float rs[256], rq[256];
    int f = blockIdx.x;            // 0..63
    int tid = threadIdx.x;
    float s = 0.f, q = 0.f;
    for (int w = tid; w < nWG; w += 256) {
        s += partial[(size_t)w * 128 + f];
        q += partial[(size_t)w * 128 + 64 + f];
    }
    rs[tid] = s; rq[tid] = q;
    __syncthreads();
    for (int st = 128; st > 0; st >>= 1) {
        if (tid < st) { rs[tid] += rs[tid + st]; rq[tid] += rq[tid + st]; }
        __syncthreads();
    }
    if (tid == 0) {
        float mean = rs[0] * inv_n;
        float var = rq[0] * inv_n - mean * mean;
        float rstd = rsqrtf(var + BN_EPS);
        float sc = gamma[f] * rstd;
        ss[f] = sc;
        ss[64 + f] = beta[f] - mean * sc;
    }
}

// ---------------------------------------------------------------------------
// Gate via MFMA from LDS, in place on d_out (unchanged R17, proven).
// ---------------------------------------------------------------------------
__global__ __launch_bounds__(256) void gateMFMA_kernel(
    float* __restrict__ h, const float* __restrict__ ss,
    const float* __restrict__ C, int N) {
    __shared__ float tile[64 * OP];            // h fp32, then out
    __shared__ unsigned short ct[64 * WP];     // C^T bf16: ct[n][k] = C[k][n]
    int tid = threadIdx.x;
    int lane = tid & 63;
    int w = tid >> 6;
    int ar = lane & 15, g = lane >> 4;
    int rbase = blockIdx.x << 6;
    int nrows = N - rbase; if (nrows > 64) nrows = 64;

#pragma unroll
    for (int it = 0; it < 4; ++it) {
        int u = it * 256 + tid;
        int r = u >> 4, c = u & 15;
        float4 v = (r < nrows)
            ? *(const float4*)(h + (size_t)(rbase + r) * D + c * 4)
            : make_float4(0.f, 0.f, 0.f, 0.f);
        *(float4*)(tile + r * OP + c * 4) = v;
    }
    {
        int k = tid >> 2, q = tid & 3;          // row k of C, 16-col chunk q
        const float* cp = C + (size_t)k * D + q * 16;
#pragma unroll
        for (int i = 0; i < 16; ++i)
            ct[(q * 16 + i) * WP + k] = (unsigned short)f2bf(cp[i]);
    }
    __syncthreads();

    bool valid = (rbase + w * 16) < N;
    f32x4 acc[4];
    if (valid) {
        const float* arow = tile + (w * 16 + ar) * OP + 8 * g;
        float4 s0 = *(const float4*)(ss + 8 * g);
        float4 s1 = *(const float4*)(ss + 8 * g + 4);
        float4 o0 = *(const float4*)(ss + 64 + 8 * g);
        float4 o1 = *(const float4*)(ss + 64 + 8 * g + 4);
        float4 v0 = ((const float4*)arow)[0];
        float4 v1 = ((const float4*)arow)[1];
        bf16x8 a0, a1;
        a0[0] = (short)f2bf(v0.x * s0.x + o0.x);
        a0[1] = (short)f2bf(v0.y * s0.y + o0.y);
        a0[2] = (short)f2bf(v0.z * s0.z + o0.z);
        a0[3] = (short)f2bf(v0.w * s0.w + o0.w);
        a0[4] = (short)f2bf(v1.x * s1.x + o1.x);
        a0[5] = (short)f2bf(v1.y * s1.y + o1.y);
        a0[6] = (short)f2bf(v1.z * s1.z + o1.z);
        a0[7] = (short)f2bf(v1.w * s1.w + o1.w);
        float4 t0 = *(const float4*)(ss + 32 + 8 * g);
        float4 t1 = *(const float4*)(ss + 32 + 8 * g + 4);
        float4 u0 = *(const float4*)(ss + 96 + 8 * g);
        float4 u1 = *(const float4*)(ss + 96 + 8 * g + 4);
        float4 w0 = ((const float4*)(arow + 32))[0];
        float4 w1 = ((const float4*)(arow + 32))[1];
        a1[0] = (short)f2bf(w0.x * t0.x + u0.x);
        a1[1] = (short)f2bf(w0.y * t0.y + u0.y);
        a1[2] = (short)f2bf(w0.z * t0.z + u0.z);
        a1[3] = (short)f2bf(w0.w * t0.w + u0.w);
        a1[4] = (short)f2bf(w1.x * t1.x + u1.x);
        a1[5] = (short)f2bf(w1.y * t1.y + u1.y);
        a1[6] = (short)f2bf(w1.z * t1.z + u1.z);
        a1[7] = (short)f2bf(w1.w * t1.w + u1.w);
#pragma unroll
        for (int t = 0; t < 4; ++t) {
            bf16x8 b0 = *(const bf16x8*)(ct + (t * 16 + ar) * WP + 8 * g);
            bf16x8 b1 = *(const bf16x8*)(ct + (t * 16 + ar) * WP + 32 + 8 * g);
            acc[t][0] = 0.f; acc[t][1] = 0.f; acc[t][2] = 0.f; acc[t][3] = 0.f;
            acc[t] = __builtin_amdgcn_mfma_f32_16x16x32_bf16(a0, b0, acc[t], 0, 0, 0);
            acc[t] = __builtin_amdgcn_mfma_f32_16x16x32_bf16(a1, b1, acc[t], 0, 0, 0);
        }
#pragma unroll
        for (int t = 0; t < 4; ++t) {
            float scC = ss[t * 16 + ar];
            float shC = ss[64 + t * 16 + ar];
#pragma unroll
            for (int r = 0; r < 4; ++r) {
                int idx = (w * 16 + 4 * g + r) * OP + t * 16 + ar;
                float hn = tile[idx] * scC + shC;
                float gg = 1.0f / (1.0f + __expf(-acc[t][r]));
                tile[idx] = gg * hn;
            }
        }
    }
    __syncthreads();

#pragma unroll
    for (int it = 0; it < 4; ++it) {
        int u = it * 256 + tid;
        int r = u >> 4, c = u & 15;
        if (r < nrows)
            *(float4*)(h + (size_t)(rbase + r) * D + c * 4) =
                *(const float4*)(tile + r * OP + c * 4);
    }
}

// ---------------------------------------------------------------------------
extern "C" void kernel_launch(void* const* d_in, const int* in_sizes, int n_in,
                              void* d_out, int out_size, void* d_ws, size_t ws_size,
                              hipStream_t stream) {
    const float* x     = (const float*)d_in[0];
    const int*   ei    = (const int*)d_in[1];
    const float* W     = (const float*)d_in[2];
    const float* b     = (const float*)d_in[3];
    const float* gamma = (const float*)d_in[4];
    const float* beta  = (const float*)d_in[5];
    const float* C     = (const float*)d_in[6];
    float* out = (float*)d_out;

    const int N = in_sizes[0] / D;        // 100000
    const int E = in_sizes[1] / 2;        // 1200000
    const int nbins = (N + BINSZ - 1) >> NBITS;   // 782
    const int nWGlin = (N + 63) / 64;             // 1563

    // ws layout: binCursor int[nbins*16] | ss f32[128] |
    //            binBuf uint[nbins*CAP] | partial f32[nWGlin*128] | xh ushort[N*D]
    int*            binCursor = (int*)d_ws;
    float*          ss        = (float*)(binCursor + (size_t)nbins * 16);
    unsigned*       binBuf    = (unsigned*)(ss + 128);
    float*          partial   = (float*)(binBuf + (size_t)nbins * CAP);
    unsigned short* xh        = (unsigned short*)(partial + (size_t)nWGlin * 128);

    // zero cursors (must precede binA's segment-reservation atomics)
    {
        int n4 = (nbins * 16 + 128) / 4;
        zero_kernel<<<(n4 + 255) / 256, 256, 0, stream>>>((int4*)d_ws, n4);
    }
    // A) x->bf16 (fused prologue) + bin edges into per-bin segments
    {
        long long n8 = (long long)N * D / 8;
        binA_kernel<<<(E + CHUNK - 1) / CHUNK, 1024, 0, stream>>>(
            ei, binCursor, binBuf, x, xh, n8, E, nbins);
    }
    // fused sort + gather + linear(MFMA) + BN partials -> h into d_out
    fusedGLS_kernel<<<nWGlin, 1024, 0, stream>>>(xh, binBuf, binCursor, W, b, out, partial, N);
    // parallel reduce + finalize -> ss
    reduceBN_kernel<<<64, 256, 0, stream>>>(partial, gamma, beta, ss, nWGlin, 1.0f / (float)N);
    // gate via MFMA, in place
    gateMFMA_kernel<<<(N + 63) / 64, 256, 0, stream>>>(out, ss, C, N);
}

// Round 27
// 103.892 us; speedup vs baseline: 1.0585x; 1.0585x over previous
//
#include <hip/hip_runtime.h>
#include <math.h>

#define D 64
#define BN_EPS 1e-5f

#define NBITS 7                 // 128 nodes per bin
#define BINSZ 128
#define MAXBINS 800             // >= ceil(100000/128)=782
#define CAP 2048                // per-bin edge capacity (mean 1535)
#define CHUNK 4096              // edges per binA workgroup
#define BUCKET 48               // per-node capacity (Poisson(12) tail @48 ~ 1e-15)
#define OP 68                   // fp32 tile stride (272B: 16B-aligned rows)
#define WP 72                   // bf16 weight tile stride (144B: 16B-aligned rows)

typedef short bf16x8 __attribute__((ext_vector_type(8)));
typedef float f32x4 __attribute__((ext_vector_type(4)));

__device__ __forceinline__ unsigned f2bf(float f) {
    unsigned u = __float_as_uint(f);
    return (u + 0x7FFFu + ((u >> 16) & 1u)) >> 16;   // RNE
}
__device__ __forceinline__ float bf2f(unsigned short h) {
    return __uint_as_float(((unsigned)h) << 16);
}

// ---------------------------------------------------------------------------
// Prepass: x (fp32) -> xh (bf16); first blocks also zero the cursor region
// (folds the zero_kernel dispatch away). Proven R25: 104.2us total.
// ---------------------------------------------------------------------------
__global__ __launch_bounds__(256) void xhalf_kernel(
    const float* __restrict__ x, unsigned short* __restrict__ xh,
    int4* __restrict__ zp, int zn4, long long n8) {
    long long t = (long long)blockIdx.x * 256 + threadIdx.x;
    if (t < zn4) zp[t] = make_int4(0, 0, 0, 0);
    if (t >= n8) return;
    const float4* rp = (const float4*)(x + t * 8);
    float4 a = rp[0], b = rp[1];
    uint4 o;
    o.x = f2bf(a.x) | (f2bf(a.y) << 16);
    o.y = f2bf(a.z) | (f2bf(a.w) << 16);
    o.z = f2bf(b.x) | (f2bf(b.y) << 16);
    o.w = f2bf(b.z) | (f2bf(b.w) << 16);
    *(uint4*)(xh + t * 8) = o;
}

// ---------------------------------------------------------------------------
// Pass A: bin edges by dst>>7 (1024-thread WGs, CHUNK=4096, proven R12-R25).
// ---------------------------------------------------------------------------
__global__ __launch_bounds__(1024) void binA_kernel(
    const int* __restrict__ ei, int* __restrict__ binCursor,   // padded x16
    unsigned* __restrict__ binBuf, int E, int nbins) {
    __shared__ unsigned short pos[CHUNK];
    __shared__ int hist[MAXBINS];
    __shared__ int base[MAXBINS];
    int tid = threadIdx.x;
    int c0 = blockIdx.x * CHUNK;

    for (int i = tid; i < nbins; i += 1024) hist[i] = 0;
    __syncthreads();

#pragma unroll
    for (int k = 0; k < CHUNK / 1024; ++k) {
        int i = k * 1024 + tid;
        int e = c0 + i;
        if (e < E) {
            int dst = ei[E + e];
            pos[i] = (unsigned short)atomicAdd(&hist[dst >> NBITS], 1);
        }
    }
    __syncthreads();

    for (int b = tid; b < nbins; b += 1024) {
        int h = hist[b];
        base[b] = h > 0 ? atomicAdd(&binCursor[b * 16], h) : 0;
    }
    __syncthreads();

#pragma unroll
    for (int k = 0; k < CHUNK / 1024; ++k) {
        int i = k * 1024 + tid;
        int e = c0 + i;
        if (e < E) {
            int src = ei[e];
            int dst = ei[E + e];
            int b = dst >> NBITS;
            int idx = base[b] + (int)pos[i];
            if (idx < CAP)
                binBuf[(size_t)b * CAP + idx] =
                    ((unsigned)src << NBITS) | (unsigned)(dst & (BINSZ - 1));
        }
    }
}

// ---------------------------------------------------------------------------
// FUSED sort + gather + mean + root + linear(MFMA) + BN partials
// (unchanged R23/R25, proven 49.5us / passing).
// ---------------------------------------------------------------------------
__global__ __launch_bounds__(1024) void fusedGLS_kernel(
    const unsigned short* __restrict__ xh, const unsigned* __restrict__ binBuf,
    const int* __restrict__ binCursor, const float* __restrict__ W,
    const float* __restrict__ bias, float* __restrict__ h,
    float* __restrict__ partial, int N) {
    __shared__ unsigned short wt[64 * WP];     // 9.2KB  W bf16
    __shared__ unsigned short ta[64 * WP];     // 9.2KB  hpre bf16
    __shared__ float uni[64 * OP];             // 17.4KB lcsr (phase1-2) / out (phase3)
    __shared__ int hist[64];
    __shared__ float psum[16 * 32];
    int* lcsr = (int*)uni;

    int tid = threadIdx.x;
    int lane = tid & 63;
    int w = tid >> 6;                          // wave 0..15
    int rbase = blockIdx.x << 6;
    int bin = blockIdx.x >> 1, half = blockIdx.x & 1;
    int nrows = N - rbase; if (nrows > 64) nrows = 64;

    // phase 0: stage W -> bf16; zero hist
    {
        int r = tid >> 4, q = tid & 15;
        float4 v = *(const float4*)(W + (size_t)r * D + q * 4);
        uint2 o;
        o.x = f2bf(v.x) | (f2bf(v.y) << 16);
        o.y = f2bf(v.z) | (f2bf(v.w) << 16);
        *(uint2*)(wt + r * WP + q * 4) = o;
    }
    if (tid < 64) hist[tid] = 0;
    __syncthreads();

    // phase 1: inline counting sort of this half-bin (LDS atomics only)
    {
        int nE = binCursor[bin * 16]; if (nE > CAP) nE = CAP;
        const unsigned* eb = binBuf + (size_t)bin * CAP;
        for (int i = tid; i < nE; i += 1024) {
            unsigned r = eb[i];
            int dl = (int)(r & (BINSZ - 1));
            if ((dl >> 6) == half) {
                int d2 = dl & 63;
                int p = atomicAdd(&hist[d2], 1);
                if (p < BUCKET) lcsr[d2 * BUCKET + p] = (int)(r >> NBITS);
            }
        }
    }
    __syncthreads();

    // phase 2: gather 4 nodes per wave into ta rows 4w..4w+3 (bf16)
    int c = lane & 15, g = lane >> 4;
    for (int i = 0; i < 4; ++i) {
        int nl = w * 4 + i;
        int node = rbase + nl;
        if (node < N) {
            int deg = hist[nl];
            deg = __builtin_amdgcn_readfirstlane(deg);
            int trips = deg < BUCKET ? deg : BUCKET;
            int sidx = lane < BUCKET ? lcsr[nl * BUCKET + lane] : 0;
            float a0 = 0.f, a1 = 0.f, a2 = 0.f, a3 = 0.f;
            if (trips > 0) {
                int nq = (trips + 3) >> 2;        // <= 12, wave-uniform
                int last = trips - 1;
                uint2 v[12];
#pragma unroll
                for (int q = 0; q < 12; ++q) {
                    if (q < nq) {
                        int r = 4 * q + g;
                        int rc = r < trips ? r : last;
                        int s = __shfl(sidx, rc);
                        v[q] = *(const uint2*)(xh + (size_t)s * D + c * 4);
                    }
                }
#pragma unroll
                for (int q = 0; q < 12; ++q) {
                    if (q < nq) {
                        int r = 4 * q + g;
                        if (r < trips) {
                            unsigned lo = v[q].x, hi = v[q].y;
                            a0 += __uint_as_float(lo << 16);
                            a1 += __uint_as_float(lo & 0xFFFF0000u);
                            a2 += __uint_as_float(hi << 16);
                            a3 += __uint_as_float(hi & 0xFFFF0000u);
                        }
                    }
                }
            }
            a0 += __shfl_xor(a0, 16); a0 += __shfl_xor(a0, 32);
            a1 += __shfl_xor(a1, 16); a1 += __shfl_xor(a1, 32);
            a2 += __shfl_xor(a2, 16); a2 += __shfl_xor(a2, 32);
            a3 += __shfl_xor(a3, 16); a3 += __shfl_xor(a3, 32);
            float invd = deg > 0 ? 1.0f / (float)deg : 1.0f;   // /max(deg,1)
            if (g == 0) {
                uint2 rt = *(const uint2*)(xh + (size_t)node * D + c * 4);
                float f0 = __uint_as_float(rt.x << 16)         + a0 * invd;
                float f1 = __uint_as_float(rt.x & 0xFFFF0000u) + a1 * invd;
                float f2 = __uint_as_float(rt.y << 16)         + a2 * invd;
                float f3 = __uint_as_float(rt.y & 0xFFFF0000u) + a3 * invd;
                uint2 o;
                o.x = f2bf(f0) | (f2bf(f1) << 16);
                o.y = f2bf(f2) | (f2bf(f3) << 16);
                *(uint2*)(ta + nl * WP + c * 4) = o;
            }
        } else if (g == 0) {
            *(uint2*)(ta + nl * WP + c * 4) = make_uint2(0u, 0u);
        }
    }
    __syncthreads();   // ta complete; all lcsr reads done (uni now free)

    // phase 3: MFMA. wave w -> row-block rb=w&3, col-chunk t=w>>2.
    int rb = w & 3, t = w >> 2;
    int ar = lane & 15, gg = lane >> 4;
    bf16x8 A0 = *(const bf16x8*)(ta + (rb * 16 + ar) * WP + 8 * gg);
    bf16x8 A1 = *(const bf16x8*)(ta + (rb * 16 + ar) * WP + 32 + 8 * gg);
    bf16x8 B0 = *(const bf16x8*)(wt + (t * 16 + ar) * WP + 8 * gg);
    bf16x8 B1 = *(const bf16x8*)(wt + (t * 16 + ar) * WP + 32 + 8 * gg);
    float bj = bias[t * 16 + ar];
    f32x4 acc;
    acc[0] = bj; acc[1] = bj; acc[2] = bj; acc[3] = bj;
    acc = __builtin_amdgcn_mfma_f32_16x16x32_bf16(A0, B0, acc, 0, 0, 0);
    acc = __builtin_amdgcn_mfma_f32_16x16x32_bf16(A1, B1, acc, 0, 0, 0);

    // write output block into uni (lcsr dead since pre-MFMA barrier)
#pragma unroll
    for (int r = 0; r < 4; ++r)
        uni[(rb * 16 + 4 * gg + r) * OP + t * 16 + ar] = acc[r];
    float s = 0.f, q = 0.f;
#pragma unroll
    for (int r = 0; r < 4; ++r) {
        int row = rb * 16 + 4 * gg + r;
        float v = (row < nrows) ? acc[r] : 0.f;
        s += v; q += v * v;
    }
    s += __shfl_xor(s, 16); s += __shfl_xor(s, 32);
    q += __shfl_xor(q, 16); q += __shfl_xor(q, 32);
    if (lane < 16) {
        psum[w * 32 + lane] = s;
        psum[w * 32 + 16 + lane] = q;
    }
    __syncthreads();

    // contiguous store (1024 threads = 64 rows x 16 quads)
    {
        int r = tid >> 4, cq = tid & 15;
        if (r < nrows)
            *(float4*)(h + (size_t)(rbase + r) * D + cq * 4) =
                *(const float4*)(uni + r * OP + cq * 4);
    }
    // per-WG partial write
    if (tid < 128) {
        int f = tid & 63;
        int off = (tid >= 64) ? 16 : 0;
        int t2 = f >> 4, col = f & 15;
        float a = 0.f;
#pragma unroll
        for (int rb2 = 0; rb2 < 4; ++rb2)
            a += psum[(t2 * 4 + rb2) * 32 + off + col];
        partial[(size_t)blockIdx.x * 128 + tid] = a;
    }
}

// ---------------------------------------------------------------------------
// Parallel BN reduce + finalize (unchanged R17).
// ---------------------------------------------------------------------------
__global__ __launch_bounds__(256) void reduceBN_kernel(
    const float* __restrict__ partial, const float* __restrict__ gamma,
    const float* __restrict__ beta, float* __restrict__ ss,
    int nWG, float inv_n) {
    __shared__ float rs[256], rq[256];
    int f = blockIdx.x;            // 0..63
    int tid = threadIdx.x;
    float s = 0.f, q = 0.f;
    for (int w = tid; w < nWG; w += 256) {
        s += partial[(size_t)w * 128 + f];
        q += partial[(size_t)w * 128 + 64 + f];
    }
    rs[tid] = s; rq[tid] = q;
    __syncthreads();
    for (int st = 128; st > 0; st >>= 1) {
        if (tid < st) { rs[tid] += rs[tid + st]; rq[tid] += rq[tid + st]; }
        __syncthreads();
    }
    if (tid == 0) {
        float mean = rs[0] * inv_n;
        float var = rq[0] * inv_n - mean * mean;
        float rstd = rsqrtf(var + BN_EPS);
        float sc = gamma[f] * rstd;
        ss[f] = sc;
        ss[64 + f] = beta[f] - mean * sc;
    }
}

// ---------------------------------------------------------------------------
// Gate via MFMA from LDS, in place on d_out (unchanged R17, proven).
// ---------------------------------------------------------------------------
__global__ __launch_bounds__(256) void gateMFMA_kernel(
    float* __restrict__ h, const float* __restrict__ ss,
    const float* __restrict__ C, int N) {
    __shared__ float tile[64 * OP];            // h fp32, then out
    __shared__ unsigned short ct[64 * WP];     // C^T bf16: ct[n][k] = C[k][n]
    int tid = threadIdx.x;
    int lane = tid & 63;
    int w = tid >> 6;
    int ar = lane & 15, g = lane >> 4;
    int rbase = blockIdx.x << 6;
    int nrows = N - rbase; if (nrows > 64) nrows = 64;

#pragma unroll
    for (int it = 0; it < 4; ++it) {
        int u = it * 256 + tid;
        int r = u >> 4, c = u & 15;
        float4 v = (r < nrows)
            ? *(const float4*)(h + (size_t)(rbase + r) * D + c * 4)
            : make_float4(0.f, 0.f, 0.f, 0.f);
        *(float4*)(tile + r * OP + c * 4) = v;
    }
    {
        int k = tid >> 2, q = tid & 3;          // row k of C, 16-col chunk q
        const float* cp = C + (size_t)k * D + q * 16;
#pragma unroll
        for (int i = 0; i < 16; ++i)
            ct[(q * 16 + i) * WP + k] = (unsigned short)f2bf(cp[i]);
    }
    __syncthreads();

    bool valid = (rbase + w * 16) < N;
    f32x4 acc[4];
    if (valid) {
        const float* arow = tile + (w * 16 + ar) * OP + 8 * g;
        float4 s0 = *(const float4*)(ss + 8 * g);
        float4 s1 = *(const float4*)(ss + 8 * g + 4);
        float4 o0 = *(const float4*)(ss + 64 + 8 * g);
        float4 o1 = *(const float4*)(ss + 64 + 8 * g + 4);
        float4 v0 = ((const float4*)arow)[0];
        float4 v1 = ((const float4*)arow)[1];
        bf16x8 a0, a1;
        a0[0] = (short)f2bf(v0.x * s0.x + o0.x);
        a0[1] = (short)f2bf(v0.y * s0.y + o0.y);
        a0[2] = (short)f2bf(v0.z * s0.z + o0.z);
        a0[3] = (short)f2bf(v0.w * s0.w + o0.w);
        a0[4] = (short)f2bf(v1.x * s1.x + o1.x);
        a0[5] = (short)f2bf(v1.y * s1.y + o1.y);
        a0[6] = (short)f2bf(v1.z * s1.z + o1.z);
        a0[7] = (short)f2bf(v1.w * s1.w + o1.w);
        float4 t0 = *(const float4*)(ss + 32 + 8 * g);
        float4 t1 = *(const float4*)(ss + 32 + 8 * g + 4);
        float4 u0 = *(const float4*)(ss + 96 + 8 * g);
        float4 u1 = *(const float4*)(ss + 96 + 8 * g + 4);
        float4 w0 = ((const float4*)(arow + 32))[0];
        float4 w1 = ((const float4*)(arow + 32))[1];
        a1[0] = (short)f2bf(w0.x * t0.x + u0.x);
        a1[1] = (short)f2bf(w0.y * t0.y + u0.y);
        a1[2] = (short)f2bf(w0.z * t0.z + u0.z);
        a1[3] = (short)f2bf(w0.w * t0.w + u0.w);
        a1[4] = (short)f2bf(w1.x * t1.x + u1.x);
        a1[5] = (short)f2bf(w1.y * t1.y + u1.y);
        a1[6] = (short)f2bf(w1.z * t1.z + u1.z);
        a1[7] = (short)f2bf(w1.w * t1.w + u1.w);
#pragma unroll
        for (int t = 0; t < 4; ++t) {
            bf16x8 b0 = *(const bf16x8*)(ct + (t * 16 + ar) * WP + 8 * g);
            bf16x8 b1 = *(const bf16x8*)(ct + (t * 16 + ar) * WP + 32 + 8 * g);
            acc[t][0] = 0.f; acc[t][1] = 0.f; acc[t][2] = 0.f; acc[t][3] = 0.f;
            acc[t] = __builtin_amdgcn_mfma_f32_16x16x32_bf16(a0, b0, acc[t], 0, 0, 0);
            acc[t] = __builtin_amdgcn_mfma_f32_16x16x32_bf16(a1, b1, acc[t], 0, 0, 0);
        }
#pragma unroll
        for (int t = 0; t < 4; ++t) {
            float scC = ss[t * 16 + ar];
            float shC = ss[64 + t * 16 + ar];
#pragma unroll
            for (int r = 0; r < 4; ++r) {
                int idx = (w * 16 + 4 * g + r) * OP + t * 16 + ar;
                float hn = tile[idx] * scC + shC;
                float gg = 1.0f / (1.0f + __expf(-acc[t][r]));
                tile[idx] = gg * hn;
            }
        }
    }
    __syncthreads();

#pragma unroll
    for (int it = 0; it < 4; ++it) {
        int u = it * 256 + tid;
        int r = u >> 4, c = u & 15;
        if (r < nrows)
            *(float4*)(h + (size_t)(rbase + r) * D + c * 4) =
                *(const float4*)(tile + r * OP + c * 4);
    }
}

// ---------------------------------------------------------------------------
extern "C" void kernel_launch(void* const* d_in, const int* in_sizes, int n_in,
                              void* d_out, int out_size, void* d_ws, size_t ws_size,
                              hipStream_t stream) {
    const float* x     = (const float*)d_in[0];
    const int*   ei    = (const int*)d_in[1];
    const float* W     = (const float*)d_in[2];
    const float* b     = (const float*)d_in[3];
    const float* gamma = (const float*)d_in[4];
    const float* beta  = (const float*)d_in[5];
    const float* C     = (const float*)d_in[6];
    float* out = (float*)d_out;

    const int N = in_sizes[0] / D;        // 100000
    const int E = in_sizes[1] / 2;        // 1200000
    const int nbins = (N + BINSZ - 1) >> NBITS;   // 782
    const int nWGlin = (N + 63) / 64;             // 1563

    // ws layout: binCursor int[nbins*16] | ss f32[128] |
    //            binBuf uint[nbins*CAP] | partial f32[nWGlin*128] | xh ushort[N*D]
    int*            binCursor = (int*)d_ws;
    float*          ss        = (float*)(binCursor + (size_t)nbins * 16);
    unsigned*       binBuf    = (unsigned*)(ss + 128);
    float*          partial   = (float*)(binBuf + (size_t)nbins * CAP);
    unsigned short* xh        = (unsigned short*)(partial + (size_t)nWGlin * 128);

    // x -> bf16, cursor zeroing folded into the first blocks
    {
        long long n8 = (long long)N * D / 8;
        int zn4 = (nbins * 16 + 128) / 4;
        xhalf_kernel<<<(int)((n8 + 255) / 256), 256, 0, stream>>>(
            x, xh, (int4*)d_ws, zn4, n8);
    }
    // A) bin edges into per-bin segments
    binA_kernel<<<(E + CHUNK - 1) / CHUNK, 1024, 0, stream>>>(ei, binCursor, binBuf, E, nbins);
    // fused sort + gather + linear(MFMA) + BN partials -> h into d_out
    fusedGLS_kernel<<<nWGlin, 1024, 0, stream>>>(xh, binBuf, binCursor, W, b, out, partial, N);
    // parallel reduce + finalize -> ss
    reduceBN_kernel<<<64, 256, 0, stream>>>(partial, gamma, beta, ss, nWGlin, 1.0f / (float)N);
    // gate via MFMA, in place
    gateMFMA_kernel<<<(N + 63) / 64, 256, 0, stream>>>(out, ss, C, N);
}